// Round 8
// baseline (312.708 us; speedup 1.0000x reference)
//
#include <hip/hip_runtime.h>
#include <math.h>

#define NN   10000
#define DEG  16
#define SS   128
#define NRBF 20
#define GG   64
#define RC   10.0f
#define PI_F 3.14159265358979323846f
#define NBK  8           // nodes per block
#define PADN 10          // LDS row stride in floats (8 nodes + 2 pad)
#define NBLK (NN/NBK)    // 1250 blocks

__device__ __forceinline__ float silu_f(float x){
    return x / (1.0f + __expf(-x));
}

// ---------------------------------------------------------------------------
// SINGLE fused kernel: phi prologue (redundant per block) -> edge phase ->
// update phase -> atomic graph accumulate -> last-block readout.
// gs (G*S floats) and the completion counter are zeroed by a hipMemsetAsync
// issued before the launch (graph-capturable).
// ---------------------------------------------------------------------------
__global__ __launch_bounds__(128) void k_all(
    const float* __restrict__ evd, const float* __restrict__ elen,
    const int* __restrict__ ngi,
    const float* __restrict__ emb0,
    const float* __restrict__ phi_w1, const float* __restrict__ phi_b1,
    const float* __restrict__ phi_w2, const float* __restrict__ phi_b2,
    const float* __restrict__ filt_w, const float* __restrict__ filt_b,
    const float* __restrict__ u_w, const float* __restrict__ v_w,
    const float* __restrict__ upd_w1, const float* __restrict__ upd_b1,
    const float* __restrict__ upd_w2, const float* __restrict__ upd_b2,
    const float* __restrict__ out_w1, const float* __restrict__ out_b1,
    const float* __restrict__ out_w2, const float* __restrict__ out_b2,
    float* __restrict__ gs, unsigned int* __restrict__ counter,
    float* __restrict__ out){
    __shared__ float  phW[3*SS];            // phi weights (per-channel scale)
    __shared__ float  hL[SS];
    __shared__ float  rbfL[NBK*DEG*NRBF];   // [edge 128][k 20]
    __shared__ float4 edgeS[NBK*DEG];       // {mc, sx, sy, sz}
    __shared__ float  frS[NBK*DEG];         // reused: s0 in phi prologue
    __shared__ float  svT[SS*PADN];         // sv [k][node]; reused for h
    __shared__ float  xT[2*SS*PADN];        // rows 0..127 Vnorm, 128..255 state
    __shared__ float  invD[NBK];
    __shared__ float  dL[NBK];
    __shared__ int    gIdx[NBK];
    __shared__ float  gRow[2][SS];
    __shared__ int    lastFlag;

    int t  = threadIdx.x;
    int nb = blockIdx.x * NBK;

    // ================= Phase 0: phi prologue (uniform state at round 0) ===
    frS[t] = 128.0f * emb0[t];              // s0
    __syncthreads();
    {
        float acc = phi_b1[t];
        #pragma unroll 4
        for (int s = 0; s < SS; s++) acc = fmaf(frS[s], phi_w1[s*SS + t], acc);
        hL[t] = silu_f(acc);
    }
    __syncthreads();
    {
        float a0 = phi_b2[t], a1 = phi_b2[SS + t], a2 = phi_b2[2*SS + t];
        #pragma unroll 4
        for (int s = 0; s < SS; s++){
            float hv = hL[s];
            const float* row = phi_w2 + s*3*SS;
            a0 = fmaf(hv, row[t],        a0);
            a1 = fmaf(hv, row[SS + t],   a1);
            a2 = fmaf(hv, row[2*SS + t], a2);
        }
        phW[t] = a0; phW[SS + t] = a1; phW[2*SS + t] = a2;
    }
    __syncthreads();

    // ================= Edge prologue: thread t owns local edge t ==========
    {
        int e = nb*DEG + t;
        float x = evd[3*e+0], y = evd[3*e+1], z = evd[3*e+2];
        float r = sqrtf(x*x + y*y + z*z);
        float len  = elen[e];
        float mask = (fabsf(len) <= RC) ? 1.0f : 0.0f;
        float cut  = (r < RC) ? 0.5f*(__cosf(PI_F*(1.0f/RC)*r) + 1.0f) : 0.0f;
        float mc   = mask * cut;
        float rs   = fmaxf(r, 1e-12f);
        frS[t]   = mask * r * r;
        edgeS[t] = make_float4(mc, x, y, z);
        float inv_rs = 1.0f / rs;
        float base   = (PI_F/RC) * rs;
        float rb[NRBF];
        #pragma unroll
        for (int k = 0; k < NRBF; k++)
            rb[k] = __sinf(base * (float)(k+1)) * inv_rs;
        float4* dst = (float4*)(rbfL + t*NRBF);
        dst[0] = make_float4(rb[0],rb[1],rb[2],rb[3]);
        dst[1] = make_float4(rb[4],rb[5],rb[6],rb[7]);
        dst[2] = make_float4(rb[8],rb[9],rb[10],rb[11]);
        dst[3] = make_float4(rb[12],rb[13],rb[14],rb[15]);
        dst[4] = make_float4(rb[16],rb[17],rb[18],rb[19]);
    }
    __syncthreads();
    if (t < NBK){
        float s = 0.0f;
        #pragma unroll
        for (int e = 0; e < DEG; e++) s += frS[t*DEG + e];
        float fb = sqrtf(s);
        invD[t] = (fb > 0.0f) ? 1.0f/fb : 1.0f;
        gIdx[t] = ngi[nb + t];
    }
    __syncthreads();
    {   // fold mc*invD into the eV components
        float4 es = edgeS[t];
        float f = es.x * invD[t >> 4];
        edgeS[t] = make_float4(es.x, es.y*f, es.z*f, es.w*f);
    }
    __syncthreads();

    // ================= Edge main loop (r6 structure) ======================
    {
        int wv = t >> 6, l = t & 63;
        int gcA = SS + l, gcB = SS + 64 + l;
        int gcC = 2*SS + l, gcD = 2*SS + 64 + l;
        float fwA[NRBF], fwB[NRBF], fwC[NRBF], fwD[NRBF];
        #pragma unroll
        for (int k = 0; k < NRBF; k++){
            fwA[k] = filt_w[k*(3*SS) + gcA];
            fwB[k] = filt_w[k*(3*SS) + gcB];
            fwC[k] = filt_w[k*(3*SS) + gcC];
            fwD[k] = filt_w[k*(3*SS) + gcD];
        }
        float fbA = filt_b[gcA], fbB = filt_b[gcB];
        float fbC = filt_b[gcC], fbD = filt_b[gcD];
        float phA = phW[gcA], phB = phW[gcB];
        float phC = phW[gcC], phD = phW[gcD];
        int s3C = l % 3, s3D = (l + 64) % 3;

        for (int ni = 0; ni < 4; ni++){
            int node = 4*wv + ni;
            float accA = 0.f, accB = 0.f, accC = 0.f, accD = 0.f;
            #pragma unroll 4
            for (int e = 0; e < DEG; e++){
                int eg = node*DEG + e;
                const float4* rv = (const float4*)(rbfL + eg*NRBF);
                float4 r0 = rv[0], r1 = rv[1], r2 = rv[2], r3 = rv[3], r4 = rv[4];
                float rr[NRBF] = {r0.x,r0.y,r0.z,r0.w, r1.x,r1.y,r1.z,r1.w,
                                  r2.x,r2.y,r2.z,r2.w, r3.x,r3.y,r3.z,r3.w,
                                  r4.x,r4.y,r4.z,r4.w};
                float4 es = edgeS[eg];
                float wA = fbA, wB = fbB, wC = fbC, wD = fbD;
                #pragma unroll
                for (int k = 0; k < NRBF; k++){
                    wA = fmaf(rr[k], fwA[k], wA);
                    wB = fmaf(rr[k], fwB[k], wB);
                    wC = fmaf(rr[k], fwC[k], wC);
                    wD = fmaf(rr[k], fwD[k], wD);
                }
                float fC = (s3C == 0) ? es.y : ((s3C == 1) ? es.z : es.w);
                float fD = (s3D == 0) ? es.y : ((s3D == 1) ? es.z : es.w);
                accA = fmaf(phA*es.x, wA, accA);
                accB = fmaf(phB*es.x, wB, accB);
                accC = fmaf(phC*fC,  wC, accC);
                accD = fmaf(phD*fD,  wD, accD);
            }
            xT[(SS + l)*PADN + node]      = accA;   // state ch l
            xT[(SS + 64 + l)*PADN + node] = accB;   // state ch 64+l
            svT[l*PADN + node]            = accC;   // sv ch l
            svT[(64 + l)*PADN + node]     = accD;   // sv ch 64+l
        }
    }
    __syncthreads();

    // ================= Update phase (r6 structure) ========================
    int cg = t & 31, ng = t >> 5;
    int c0 = 4*cg, n0 = 2*ng;

    // Phase A: U = sv@u_w, V = sv@v_w
    float accU[4][2], accV[4][2];
    #pragma unroll
    for (int j = 0; j < 4; j++){
        accU[j][0] = accU[j][1] = 0.f;
        accV[j][0] = accV[j][1] = 0.f;
    }
    #pragma unroll 4
    for (int k = 0; k < SS; k++){
        float2 xv = *(const float2*)(svT + k*PADN + n0);
        float4 wu = *(const float4*)(u_w + k*SS + c0);
        float4 wv4 = *(const float4*)(v_w + k*SS + c0);
        float wua[4] = {wu.x, wu.y, wu.z, wu.w};
        float wva[4] = {wv4.x, wv4.y, wv4.z, wv4.w};
        #pragma unroll
        for (int j = 0; j < 4; j++){
            accU[j][0] = fmaf(xv.x, wua[j], accU[j][0]);
            accU[j][1] = fmaf(xv.y, wua[j], accU[j][1]);
            accV[j][0] = fmaf(xv.x, wva[j], accV[j][0]);
            accV[j][1] = fmaf(xv.y, wva[j], accV[j][1]);
        }
    }
    float pd0 = 0.f, pd1 = 0.f;
    #pragma unroll
    for (int j = 0; j < 4; j++){
        pd0 = fmaf(accU[j][0], accV[j][0], pd0);
        pd1 = fmaf(accU[j][1], accV[j][1], pd1);
    }
    #pragma unroll
    for (int m = 1; m <= 16; m <<= 1){
        pd0 += __shfl_xor(pd0, m);
        pd1 += __shfl_xor(pd1, m);
    }
    if (cg == 0){ dL[n0] = pd0; dL[n0+1] = pd1; }
    const float SQ3 = 1.7320508075688772f;
    #pragma unroll
    for (int j = 0; j < 4; j++){
        xT[(c0+j)*PADN + n0]     = SQ3 * fabsf(accV[j][0]);
        xT[(c0+j)*PADN + n0 + 1] = SQ3 * fabsf(accV[j][1]);
    }
    __syncthreads();
    float d30 = 3.0f*dL[n0], d31 = 3.0f*dL[n0+1];

    // Phase B: h = silu([Vnorm,state] @ upd_w1 + b1)  -> svT reused as h
    float accH[4][2];
    #pragma unroll
    for (int j = 0; j < 4; j++) accH[j][0] = accH[j][1] = 0.f;
    #pragma unroll 4
    for (int k = 0; k < 2*SS; k++){
        float2 xv = *(const float2*)(xT + k*PADN + n0);
        float4 w4 = *(const float4*)(upd_w1 + k*SS + c0);
        float wa[4] = {w4.x, w4.y, w4.z, w4.w};
        #pragma unroll
        for (int j = 0; j < 4; j++){
            accH[j][0] = fmaf(xv.x, wa[j], accH[j][0]);
            accH[j][1] = fmaf(xv.y, wa[j], accH[j][1]);
        }
    }
    {
        float4 b1v = *(const float4*)(upd_b1 + c0);
        float ba[4] = {b1v.x, b1v.y, b1v.z, b1v.w};
        #pragma unroll
        for (int j = 0; j < 4; j++){
            svT[(c0+j)*PADN + n0]     = silu_f(accH[j][0] + ba[j]);
            svT[(c0+j)*PADN + n0 + 1] = silu_f(accH[j][1] + ba[j]);
        }
    }
    __syncthreads();

    // Phase C: a_sv (w2 cols S..2S), a_ss (cols 2S..3S)
    float a2[4][2], a3[4][2];
    #pragma unroll
    for (int j = 0; j < 4; j++){
        a2[j][0] = a2[j][1] = 0.f;
        a3[j][0] = a3[j][1] = 0.f;
    }
    #pragma unroll 4
    for (int k = 0; k < SS; k++){
        float2 hx = *(const float2*)(svT + k*PADN + n0);
        float4 w2 = *(const float4*)(upd_w2 + k*3*SS + SS   + c0);
        float4 w3 = *(const float4*)(upd_w2 + k*3*SS + 2*SS + c0);
        float w2a[4] = {w2.x, w2.y, w2.z, w2.w};
        float w3a[4] = {w3.x, w3.y, w3.z, w3.w};
        #pragma unroll
        for (int j = 0; j < 4; j++){
            a2[j][0] = fmaf(hx.x, w2a[j], a2[j][0]);
            a2[j][1] = fmaf(hx.y, w2a[j], a2[j][1]);
            a3[j][0] = fmaf(hx.x, w3a[j], a3[j][0]);
            a3[j][1] = fmaf(hx.y, w3a[j], a3[j][1]);
        }
    }
    {
        float4 bsv4 = *(const float4*)(upd_b2 + SS   + c0);
        float4 bss4 = *(const float4*)(upd_b2 + 2*SS + c0);
        float bsv[4] = {bsv4.x, bsv4.y, bsv4.z, bsv4.w};
        float bss[4] = {bss4.x, bss4.y, bss4.z, bss4.w};
        int g0 = gIdx[n0], g1 = gIdx[n0+1];
        #pragma unroll
        for (int j = 0; j < 4; j++){
            float ns0 = (a3[j][0] + bss[j]) + d30*(a2[j][0] + bsv[j]);
            float ns1 = (a3[j][1] + bss[j]) + d31*(a2[j][1] + bsv[j]);
            atomicAdd(&gs[g0*SS + c0 + j], ns0);
            atomicAdd(&gs[g1*SS + c0 + j], ns1);
        }
    }

    // ================= Last-block readout =================================
    __threadfence();
    if (t == 0){
        unsigned int v = atomicAdd(counter, 1u);
        lastFlag = (v == (unsigned int)(NBLK - 1)) ? 1 : 0;
    }
    __syncthreads();
    if (lastFlag){
        __threadfence();
        int wv = t >> 6, l = t & 63;
        int cc0 = 2*l;
        float2 ob1 = *(const float2*)(out_b1 + cc0);
        float2 ow2 = *(const float2*)(out_w2 + cc0);
        float  ob2 = out_b2[0];
        for (int g = wv; g < GG; g += 2){
            gRow[wv][l]      = __hip_atomic_load(gs + g*SS + l,
                                  __ATOMIC_RELAXED, __HIP_MEMORY_SCOPE_AGENT);
            gRow[wv][64 + l] = __hip_atomic_load(gs + g*SS + 64 + l,
                                  __ATOMIC_RELAXED, __HIP_MEMORY_SCOPE_AGENT);
            __syncthreads();
            float acc0 = ob1.x, acc1 = ob1.y;
            #pragma unroll 4
            for (int s4 = 0; s4 < SS; s4 += 4){
                float4 gv = *(const float4*)(&gRow[wv][s4]);
                float2 w0 = *(const float2*)(out_w1 + (s4+0)*SS + cc0);
                float2 w1 = *(const float2*)(out_w1 + (s4+1)*SS + cc0);
                float2 w2 = *(const float2*)(out_w1 + (s4+2)*SS + cc0);
                float2 w3 = *(const float2*)(out_w1 + (s4+3)*SS + cc0);
                acc0 = fmaf(gv.x, w0.x, acc0); acc1 = fmaf(gv.x, w0.y, acc1);
                acc0 = fmaf(gv.y, w1.x, acc0); acc1 = fmaf(gv.y, w1.y, acc1);
                acc0 = fmaf(gv.z, w2.x, acc0); acc1 = fmaf(gv.z, w2.y, acc1);
                acc0 = fmaf(gv.w, w3.x, acc0); acc1 = fmaf(gv.w, w3.y, acc1);
            }
            float p = silu_f(acc0)*ow2.x + silu_f(acc1)*ow2.y;
            #pragma unroll
            for (int off = 32; off; off >>= 1) p += __shfl_down(p, off);
            if (l == 0) out[g] = p + ob2;
            __syncthreads();
        }
    }
}

extern "C" void kernel_launch(void* const* d_in, const int* in_sizes, int n_in,
                              void* d_out, int out_size, void* d_ws, size_t ws_size,
                              hipStream_t stream) {
    const float* evd     = (const float*)d_in[0];
    const float* elen    = (const float*)d_in[1];
    const int*   ngi     = (const int*)  d_in[3];
    const float* emb0    = (const float*)d_in[5];
    const float* phi_w1  = (const float*)d_in[6];
    const float* phi_b1  = (const float*)d_in[7];
    const float* phi_w2  = (const float*)d_in[8];
    const float* phi_b2  = (const float*)d_in[9];
    const float* filt_w  = (const float*)d_in[10];
    const float* filt_b  = (const float*)d_in[11];
    const float* u_w     = (const float*)d_in[12];
    const float* v_w     = (const float*)d_in[13];
    const float* upd_w1  = (const float*)d_in[14];
    const float* upd_b1  = (const float*)d_in[15];
    const float* upd_w2  = (const float*)d_in[16];
    const float* upd_b2  = (const float*)d_in[17];
    const float* out_w1  = (const float*)d_in[18];
    const float* out_b1  = (const float*)d_in[19];
    const float* out_w2  = (const float*)d_in[20];
    const float* out_b2  = (const float*)d_in[21];

    float*        ws      = (float*)d_ws;
    float*        gs      = ws;                       // G*S floats
    unsigned int* counter = (unsigned int*)(ws + GG*SS);

    hipMemsetAsync(d_ws, 0, (GG*SS + 16)*sizeof(float), stream);
    k_all<<<NBLK, 128, 0, stream>>>(evd, elen, ngi, emb0,
                                    phi_w1, phi_b1, phi_w2, phi_b2,
                                    filt_w, filt_b, u_w, v_w,
                                    upd_w1, upd_b1, upd_w2, upd_b2,
                                    out_w1, out_b1, out_w2, out_b2,
                                    gs, counter, (float*)d_out);
}